// Round 1
// baseline (215.534 us; speedup 1.0000x reference)
//
#include <hip/hip_runtime.h>

typedef __attribute__((ext_vector_type(8))) short bf16x8;
typedef __attribute__((ext_vector_type(4))) float f32x4;

#define DEVI __device__ __forceinline__

constexpr int NB   = 16;    // batch
constexpr int CC   = 256;   // channels
constexpr int SS   = 1024;  // sequence (32*32)
constexpr int TOK  = NB * SS;
constexpr int NH   = 8;
constexpr int HD   = 32;

DEVI unsigned short f2bf(float f) {
  union { float f; unsigned u; } v; v.f = f;
  unsigned u = v.u;
  unsigned r = (u + 0x7FFFu + ((u >> 16) & 1u)) >> 16;
  return (unsigned short)r;
}

DEVI void gload16(const void* g, void* l) {
  __builtin_amdgcn_global_load_lds((const __attribute__((address_space(1))) void*)g,
                                   (__attribute__((address_space(3))) void*)l, 16, 0, 0);
}

// ---------------- weight fp32 -> bf16 ----------------
__global__ __launch_bounds__(256) void k_f2bf(const float* __restrict__ in,
                                              unsigned short* __restrict__ out, int n) {
  int i = blockIdx.x * 256 + threadIdx.x;
  if (i < n) out[i] = f2bf(in[i]);
}

// ---------------- LN1 + transpose: x[b][c][p] -> xt fp32 [tok][c], xln bf16 [tok][c] ----------------
__global__ __launch_bounds__(256) void k_ln1(const float* __restrict__ x,
                                             const float* __restrict__ g,
                                             const float* __restrict__ be,
                                             float* __restrict__ xt,
                                             unsigned short* __restrict__ xln) {
  __shared__ float tile[256][33];
  const int b  = blockIdx.y;
  const int p0 = blockIdx.x * 32;
  const int t  = threadIdx.x;
  const float* src = x + ((size_t)b * 256 + t) * 1024 + p0;
#pragma unroll
  for (int j = 0; j < 32; j += 4) {
    float4 v = *(const float4*)(src + j);
    tile[t][j] = v.x; tile[t][j + 1] = v.y; tile[t][j + 2] = v.z; tile[t][j + 3] = v.w;
  }
  __syncthreads();
  const int w = t >> 6, l = t & 63;
#pragma unroll
  for (int i = 0; i < 8; i++) {
    const int p = w * 8 + i;
    float s = 0.f, ss = 0.f;
#pragma unroll
    for (int q = 0; q < 4; q++) {
      float v = tile[l + 64 * q][p];
      s += v; ss += v * v;
    }
#pragma unroll
    for (int msk = 1; msk < 64; msk <<= 1) {
      s  += __shfl_xor(s, msk);
      ss += __shfl_xor(ss, msk);
    }
    const float mean = s * (1.f / 256.f);
    const float var  = ss * (1.f / 256.f) - mean * mean;
    const float rs   = rsqrtf(var + 1e-5f);
    const size_t token = (size_t)b * 1024 + p0 + p;
#pragma unroll
    for (int q = 0; q < 4; q++) {
      const int c = l + 64 * q;
      const float v = tile[c][p];
      xt[token * 256 + c]  = v;
      xln[token * 256 + c] = f2bf((v - mean) * rs * g[c] + be[c]);
    }
  }
}

// ---------------- GEMM: C[M,N] = A[M,K] @ B[N,K]^T, bf16 in, fp32 acc ----------------
// EPI 0: store bf16            (qkv)
// EPI 1: +bias +addend -> f32  (proj + residual)
// EPI 2: +bias, relu -> bf16   (ffn1)
// EPI 3: +bias +addend -> f32  (ffn2 + residual)
template <int EPI>
__global__ __launch_bounds__(256) void k_gemm(const unsigned short* __restrict__ A, int lda,
                                              const unsigned short* __restrict__ Bw, int ldb,
                                              int K,
                                              const float* __restrict__ bias,
                                              const float* __restrict__ addend, int ldadd,
                                              float* __restrict__ outf,
                                              unsigned short* __restrict__ outb, int ldc) {
  __shared__ __align__(16) unsigned short As[128 * 64];
  __shared__ __align__(16) unsigned short Bs[128 * 64];
  const int t  = threadIdx.x;
  const int m0 = blockIdx.x * 128, n0 = blockIdx.y * 128;
  const int w  = t >> 6, l = t & 63;
  const int wm = (w >> 1) * 64, wn = (w & 1) * 64;
  const int lr = l & 15, lk = (l >> 4) * 8;
  f32x4 acc[4][4] = {};
  const int nkt = K >> 6;
  for (int kt = 0; kt < nkt; ++kt) {
    __syncthreads();
#pragma unroll
    for (int i = 0; i < 4; i++) {
      const int e = i * 2048 + t * 8;
      const int r = e >> 6, c = e & 63;
      gload16(&A[(size_t)(m0 + r) * lda + kt * 64 + c], &As[e]);
      gload16(&Bw[(size_t)(n0 + r) * ldb + kt * 64 + c], &Bs[e]);
    }
    __syncthreads();
#pragma unroll
    for (int ks = 0; ks < 2; ks++) {
      bf16x8 af[4], bfr[4];
#pragma unroll
      for (int i = 0; i < 4; i++) af[i] = *(const bf16x8*)&As[(wm + i * 16 + lr) * 64 + ks * 32 + lk];
#pragma unroll
      for (int j = 0; j < 4; j++) bfr[j] = *(const bf16x8*)&Bs[(wn + j * 16 + lr) * 64 + ks * 32 + lk];
#pragma unroll
      for (int i = 0; i < 4; i++)
#pragma unroll
        for (int j = 0; j < 4; j++)
          acc[i][j] = __builtin_amdgcn_mfma_f32_16x16x32_bf16(af[i], bfr[j], acc[i][j], 0, 0, 0);
    }
  }
#pragma unroll
  for (int i = 0; i < 4; i++)
#pragma unroll
    for (int j = 0; j < 4; j++)
#pragma unroll
      for (int r = 0; r < 4; r++) {
        const int gr = m0 + wm + i * 16 + (l >> 4) * 4 + r;
        const int gc = n0 + wn + j * 16 + (l & 15);
        const float v = acc[i][j][r];
        if constexpr (EPI == 0) {
          outb[(size_t)gr * ldc + gc] = f2bf(v);
        } else if constexpr (EPI == 1) {
          outf[(size_t)gr * ldc + gc] = v + bias[gc] + addend[(size_t)gr * ldadd + gc];
        } else if constexpr (EPI == 2) {
          const float z = v + bias[gc];
          outb[(size_t)gr * ldc + gc] = f2bf(z > 0.f ? z : 0.f);
        } else {
          outf[(size_t)gr * ldc + gc] = v + bias[gc] + addend[(size_t)gr * ldadd + gc];
        }
      }
}

// ---------------- flash attention ----------------
// qkv bf16 [tok][768]: q at [h*32], k at [256+h*32], v at [512+h*32]
// grid: (16 q-tiles of 64 rows, 128 b*h). block 256 thr = 4 waves, 16 q-rows each.
__global__ __launch_bounds__(256) void k_attn(const unsigned short* __restrict__ qkv,
                                              unsigned short* __restrict__ attn_out) {
  __shared__ __align__(16) unsigned short Ks[64][40];
  __shared__ __align__(16) unsigned short Vt[32][72];
  __shared__ __align__(16) unsigned short Ps[4][16][72];

  const int bh = blockIdx.y;
  const int b = bh >> 3, h = bh & 7;
  const int q0 = blockIdx.x * 64;
  const int t = threadIdx.x, w = t >> 6, l = t & 63;
  const int lr = l & 15, lk = (l >> 4) * 8;
  const size_t base = (size_t)b * 1024 * 768;

  const bf16x8 qf = *(const bf16x8*)&qkv[base + (size_t)(q0 + w * 16 + lr) * 768 + h * 32 + lk];

  f32x4 o0 = {0.f, 0.f, 0.f, 0.f}, o1 = {0.f, 0.f, 0.f, 0.f};
  float m[4] = {-3e38f, -3e38f, -3e38f, -3e38f};
  float lsum[4] = {0.f, 0.f, 0.f, 0.f};
  const float scale = 0.17677669529663687f;  // 1/sqrt(32)
  const f32x4 z4 = {0.f, 0.f, 0.f, 0.f};

  for (int kc = 0; kc < 16; kc++) {
    const int tok = kc * 64 + (t >> 2);
    const int d0  = (t & 3) * 8;
    const bf16x8 kv_k = *(const bf16x8*)&qkv[base + (size_t)tok * 768 + 256 + h * 32 + d0];
    const bf16x8 kv_v = *(const bf16x8*)&qkv[base + (size_t)tok * 768 + 512 + h * 32 + d0];
    __syncthreads();  // previous iteration's LDS reads done
    *(bf16x8*)&Ks[t >> 2][d0] = kv_k;
#pragma unroll
    for (int j = 0; j < 8; j++) Vt[d0 + j][t >> 2] = ((const unsigned short*)&kv_v)[j];
    __syncthreads();

    f32x4 s[4];
#pragma unroll
    for (int j = 0; j < 4; j++) {
      const bf16x8 kf = *(const bf16x8*)&Ks[j * 16 + lr][lk];
      s[j] = __builtin_amdgcn_mfma_f32_16x16x32_bf16(qf, kf, z4, 0, 0, 0);
    }
#pragma unroll
    for (int r = 0; r < 4; r++) {
      float mx = s[0][r];
      mx = fmaxf(mx, s[1][r]); mx = fmaxf(mx, s[2][r]); mx = fmaxf(mx, s[3][r]);
      mx *= scale;
#pragma unroll
      for (int msk = 1; msk < 16; msk <<= 1) mx = fmaxf(mx, __shfl_xor(mx, msk));
      const float mnew  = fmaxf(m[r], mx);
      const float alpha = __expf(m[r] - mnew);
      float ps = 0.f;
#pragma unroll
      for (int j = 0; j < 4; j++) {
        const float p = __expf(s[j][r] * scale - mnew);
        ps += p;
        Ps[w][(l >> 4) * 4 + r][(l & 15) + 16 * j] = f2bf(p);
      }
#pragma unroll
      for (int msk = 1; msk < 16; msk <<= 1) ps += __shfl_xor(ps, msk);
      lsum[r] = lsum[r] * alpha + ps;
      m[r] = mnew;
      o0[r] *= alpha; o1[r] *= alpha;
    }
#pragma unroll
    for (int ks = 0; ks < 2; ks++) {
      const bf16x8 pa  = *(const bf16x8*)&Ps[w][lr][ks * 32 + lk];
      const bf16x8 v0f = *(const bf16x8*)&Vt[lr][ks * 32 + lk];
      const bf16x8 v1f = *(const bf16x8*)&Vt[16 + lr][ks * 32 + lk];
      o0 = __builtin_amdgcn_mfma_f32_16x16x32_bf16(pa, v0f, o0, 0, 0, 0);
      o1 = __builtin_amdgcn_mfma_f32_16x16x32_bf16(pa, v1f, o1, 0, 0, 0);
    }
  }
#pragma unroll
  for (int r = 0; r < 4; r++) {
    const int row = q0 + w * 16 + (l >> 4) * 4 + r;
    const float inv = 1.f / lsum[r];
    attn_out[(size_t)(b * 1024 + row) * 256 + h * 32 + (l & 15)]      = f2bf(o0[r] * inv);
    attn_out[(size_t)(b * 1024 + row) * 256 + h * 32 + 16 + (l & 15)] = f2bf(o1[r] * inv);
  }
}

// ---------------- LN2: y fp32 [tok][256] -> yln bf16 ----------------
__global__ __launch_bounds__(256) void k_ln2(const float* __restrict__ y,
                                             const float* __restrict__ g,
                                             const float* __restrict__ be,
                                             unsigned short* __restrict__ yln) {
  const int row = blockIdx.x * 4 + (threadIdx.x >> 6);
  const int l = threadIdx.x & 63;
  const float* yr = y + (size_t)row * 256;
  const float4 v = *(const float4*)(yr + l * 4);
  float s  = v.x + v.y + v.z + v.w;
  float ss = v.x * v.x + v.y * v.y + v.z * v.z + v.w * v.w;
#pragma unroll
  for (int msk = 1; msk < 64; msk <<= 1) {
    s  += __shfl_xor(s, msk);
    ss += __shfl_xor(ss, msk);
  }
  const float mean = s * (1.f / 256.f);
  const float var  = ss * (1.f / 256.f) - mean * mean;
  const float rs   = rsqrtf(var + 1e-5f);
  const float4 gv  = *(const float4*)(g + l * 4);
  const float4 bv  = *(const float4*)(be + l * 4);
  ushort4 o;
  o.x = f2bf((v.x - mean) * rs * gv.x + bv.x);
  o.y = f2bf((v.y - mean) * rs * gv.y + bv.y);
  o.z = f2bf((v.z - mean) * rs * gv.z + bv.z);
  o.w = f2bf((v.w - mean) * rs * gv.w + bv.w);
  *(ushort4*)&yln[(size_t)row * 256 + l * 4] = o;
}

// ---------------- output transpose: z[b][s][c] -> out[b][c][s] ----------------
__global__ __launch_bounds__(256) void k_tout(const float* __restrict__ z,
                                              float* __restrict__ out) {
  __shared__ float tile[32][33];
  const int b  = blockIdx.z;
  const int c0 = blockIdx.y * 32, p0 = blockIdx.x * 32;
  const int tx = threadIdx.x & 31, ty = threadIdx.x >> 5;
#pragma unroll
  for (int i = 0; i < 32; i += 8)
    tile[ty + i][tx] = z[((size_t)b * 1024 + p0 + ty + i) * 256 + c0 + tx];
  __syncthreads();
#pragma unroll
  for (int i = 0; i < 32; i += 8)
    out[((size_t)b * 256 + c0 + ty + i) * 1024 + p0 + tx] = tile[tx][ty + i];
}

// ---------------- launch ----------------
extern "C" void kernel_launch(void* const* d_in, const int* in_sizes, int n_in,
                              void* d_out, int out_size, void* d_ws, size_t ws_size,
                              hipStream_t stream) {
  const float* x      = (const float*)d_in[0];
  const float* w_qkv  = (const float*)d_in[1];
  const float* w_proj = (const float*)d_in[2];
  const float* b_proj = (const float*)d_in[3];
  const float* g1     = (const float*)d_in[4];
  const float* beta1  = (const float*)d_in[5];
  const float* g2     = (const float*)d_in[6];
  const float* beta2  = (const float*)d_in[7];
  const float* w1     = (const float*)d_in[8];
  const float* b1     = (const float*)d_in[9];
  const float* w2     = (const float*)d_in[10];
  const float* b2     = (const float*)d_in[11];
  float* out = (float*)d_out;
  char* ws = (char*)d_ws;

  // workspace layout (bytes); h1 aliases xln+qkv, z aliases xt (liveness-safe)
  constexpr size_t OFF_XT  = 0;                       // 16 MB fp32 [tok][256]
  constexpr size_t OFF_XLN = 16777216;                //  8 MB bf16
  constexpr size_t OFF_QKV = OFF_XLN + 8388608;       // 24 MB bf16 [tok][768]
  constexpr size_t OFF_ATT = OFF_QKV + 25165824;      //  8 MB bf16
  constexpr size_t OFF_Y   = OFF_ATT + 8388608;       // 16 MB fp32
  constexpr size_t OFF_YLN = OFF_Y + 16777216;        //  8 MB bf16
  constexpr size_t OFF_W   = OFF_YLN + 8388608;       // weights bf16
  constexpr size_t OFF_H1  = OFF_XLN;                 // alias: 32 MB bf16 [tok][1024]
  constexpr size_t OFF_Z   = OFF_XT;                  // alias: 16 MB fp32

  float*          xt    = (float*)(ws + OFF_XT);
  unsigned short* xln   = (unsigned short*)(ws + OFF_XLN);
  unsigned short* qkv   = (unsigned short*)(ws + OFF_QKV);
  unsigned short* attn  = (unsigned short*)(ws + OFF_ATT);
  float*          y     = (float*)(ws + OFF_Y);
  unsigned short* yln   = (unsigned short*)(ws + OFF_YLN);
  unsigned short* h1    = (unsigned short*)(ws + OFF_H1);
  float*          z     = (float*)(ws + OFF_Z);
  unsigned short* wqkvb = (unsigned short*)(ws + OFF_W);
  unsigned short* wprjb = (unsigned short*)(ws + OFF_W + 393216);
  unsigned short* w1b   = (unsigned short*)(ws + OFF_W + 393216 + 131072);
  unsigned short* w2b   = (unsigned short*)(ws + OFF_W + 393216 + 131072 + 524288);

  k_f2bf<<<768, 256, 0, stream>>>(w_qkv, wqkvb, 768 * 256);
  k_f2bf<<<256, 256, 0, stream>>>(w_proj, wprjb, 256 * 256);
  k_f2bf<<<1024, 256, 0, stream>>>(w1, w1b, 1024 * 256);
  k_f2bf<<<1024, 256, 0, stream>>>(w2, w2b, 256 * 1024);

  k_ln1<<<dim3(32, 16), 256, 0, stream>>>(x, g1, beta1, xt, xln);

  // qkv = xln @ w_qkv^T  [16384, 768]
  k_gemm<0><<<dim3(128, 6), 256, 0, stream>>>(xln, 256, wqkvb, 256, 256,
                                              nullptr, nullptr, 0, nullptr, qkv, 768);

  k_attn<<<dim3(16, 128), 256, 0, stream>>>(qkv, attn);

  // y = attn @ w_proj^T + b_proj + xt   [16384, 256] fp32
  k_gemm<1><<<dim3(128, 2), 256, 0, stream>>>(attn, 256, wprjb, 256, 256,
                                              b_proj, xt, 256, y, nullptr, 256);

  k_ln2<<<4096, 256, 0, stream>>>(y, g2, beta2, yln);

  // h1 = relu(yln @ w1^T + b1)  [16384, 1024] bf16
  k_gemm<2><<<dim3(128, 8), 256, 0, stream>>>(yln, 256, w1b, 256, 256,
                                              b1, nullptr, 0, nullptr, h1, 1024);

  // z = h1 @ w2^T + b2 + y  [16384, 256] fp32
  k_gemm<3><<<dim3(128, 2), 256, 0, stream>>>(h1, 1024, w2b, 1024, 1024,
                                              b2, y, 256, z, nullptr, 256);

  k_tout<<<dim3(32, 8, 16), 256, 0, stream>>>(z, out);
}

// Round 2
// 158.341 us; speedup vs baseline: 1.3612x; 1.3612x over previous
//
#include <hip/hip_runtime.h>
#include <hip/hip_bf16.h>

typedef __attribute__((ext_vector_type(8))) short bf16x8;
typedef __attribute__((ext_vector_type(4))) float f32x4;

#define DEVI __device__ __forceinline__

DEVI unsigned short f2bf(float f) {
  __hip_bfloat16 h = __float2bfloat16(f);
  return *reinterpret_cast<unsigned short*>(&h);
}

DEVI void gload16(const void* g, void* l) {
  __builtin_amdgcn_global_load_lds((const __attribute__((address_space(1))) void*)g,
                                   (__attribute__((address_space(3))) void*)l, 16, 0, 0);
}

// ---------------- weight fp32 -> bf16 ----------------
__global__ __launch_bounds__(256) void k_f2bf(const float* __restrict__ in,
                                              unsigned short* __restrict__ out, int n) {
  int i = blockIdx.x * 256 + threadIdx.x;
  if (i < n) out[i] = f2bf(in[i]);
}

// ---------------- LN1 + transpose: x[b][c][p] -> xt fp32 [tok][c], xln bf16 [tok][c] ----------------
__global__ __launch_bounds__(256) void k_ln1(const float* __restrict__ x,
                                             const float* __restrict__ g,
                                             const float* __restrict__ be,
                                             float* __restrict__ xt,
                                             unsigned short* __restrict__ xln) {
  __shared__ float tile[256][33];
  const int b  = blockIdx.y;
  const int p0 = blockIdx.x * 32;
  const int t  = threadIdx.x;
  const float* src = x + ((size_t)b * 256 + t) * 1024 + p0;
#pragma unroll
  for (int j = 0; j < 32; j += 4) {
    float4 v = *(const float4*)(src + j);
    tile[t][j] = v.x; tile[t][j + 1] = v.y; tile[t][j + 2] = v.z; tile[t][j + 3] = v.w;
  }
  __syncthreads();
  const int w = t >> 6, l = t & 63;
#pragma unroll
  for (int i = 0; i < 8; i++) {
    const int p = w * 8 + i;
    float s = 0.f, ss = 0.f;
#pragma unroll
    for (int q = 0; q < 4; q++) {
      float v = tile[l + 64 * q][p];
      s += v; ss += v * v;
    }
#pragma unroll
    for (int msk = 1; msk < 64; msk <<= 1) {
      s  += __shfl_xor(s, msk);
      ss += __shfl_xor(ss, msk);
    }
    const float mean = s * (1.f / 256.f);
    const float var  = ss * (1.f / 256.f) - mean * mean;
    const float rs   = rsqrtf(var + 1e-5f);
    const size_t token = (size_t)b * 1024 + p0 + p;
#pragma unroll
    for (int q = 0; q < 4; q++) {
      const int c = l + 64 * q;
      const float v = tile[c][p];
      xt[token * 256 + c]  = v;
      xln[token * 256 + c] = f2bf((v - mean) * rs * g[c] + be[c]);
    }
  }
}

// ---------------- GEMM: C[M,N] = A[M,K] @ B[N,K]^T, bf16 in, fp32 acc ----------------
template <int EPI>
__global__ __launch_bounds__(256) void k_gemm(const unsigned short* __restrict__ A, int lda,
                                              const unsigned short* __restrict__ Bw, int ldb,
                                              int K,
                                              const float* __restrict__ bias,
                                              const float* __restrict__ addend, int ldadd,
                                              float* __restrict__ outf,
                                              unsigned short* __restrict__ outb, int ldc) {
  __shared__ __align__(16) unsigned short As[128 * 64];
  __shared__ __align__(16) unsigned short Bs[128 * 64];
  const int t  = threadIdx.x;
  const int m0 = blockIdx.x * 128, n0 = blockIdx.y * 128;
  const int w  = t >> 6, l = t & 63;
  const int wm = (w >> 1) * 64, wn = (w & 1) * 64;
  const int lr = l & 15, lk = (l >> 4) * 8;
  f32x4 acc[4][4] = {};
  const int nkt = K >> 6;
  for (int kt = 0; kt < nkt; ++kt) {
    __syncthreads();
#pragma unroll
    for (int i = 0; i < 4; i++) {
      const int e = i * 2048 + t * 8;
      const int r = e >> 6, c = e & 63;
      gload16(&A[(size_t)(m0 + r) * lda + kt * 64 + c], &As[e]);
      gload16(&Bw[(size_t)(n0 + r) * ldb + kt * 64 + c], &Bs[e]);
    }
    __syncthreads();
#pragma unroll
    for (int ks = 0; ks < 2; ks++) {
      bf16x8 af[4], bfr[4];
#pragma unroll
      for (int i = 0; i < 4; i++) af[i] = *(const bf16x8*)&As[(wm + i * 16 + lr) * 64 + ks * 32 + lk];
#pragma unroll
      for (int j = 0; j < 4; j++) bfr[j] = *(const bf16x8*)&Bs[(wn + j * 16 + lr) * 64 + ks * 32 + lk];
#pragma unroll
      for (int i = 0; i < 4; i++)
#pragma unroll
        for (int j = 0; j < 4; j++)
          acc[i][j] = __builtin_amdgcn_mfma_f32_16x16x32_bf16(af[i], bfr[j], acc[i][j], 0, 0, 0);
    }
  }
#pragma unroll
  for (int i = 0; i < 4; i++)
#pragma unroll
    for (int j = 0; j < 4; j++)
#pragma unroll
      for (int r = 0; r < 4; r++) {
        const int gr = m0 + wm + i * 16 + (l >> 4) * 4 + r;
        const int gc = n0 + wn + j * 16 + (l & 15);
        const float v = acc[i][j][r];
        if constexpr (EPI == 0) {
          outb[(size_t)gr * ldc + gc] = f2bf(v);
        } else if constexpr (EPI == 1) {
          outf[(size_t)gr * ldc + gc] = v + bias[gc] + addend[(size_t)gr * ldadd + gc];
        } else if constexpr (EPI == 2) {
          const float z = v + bias[gc];
          outb[(size_t)gr * ldc + gc] = f2bf(z > 0.f ? z : 0.f);
        } else {
          outf[(size_t)gr * ldc + gc] = v + bias[gc] + addend[(size_t)gr * ldadd + gc];
        }
      }
}

// ---------------- flash attention (swapped QK^T + defer-max) ----------------
// qkv bf16 [tok][768]: q at [h*32], k at [256+h*32], v at [512+h*32]
// 1024 blocks (XCD-swizzled): 8 q-tiles of 128 rows x 128 bh. 4 waves; wave = 32 q rows.
__global__ __launch_bounds__(256) void k_attn(const unsigned short* __restrict__ qkv,
                                              unsigned short* __restrict__ attn_out) {
  __shared__ __align__(16) unsigned short Ks[64][40];
  __shared__ __align__(16) unsigned short Vt[32][72];
  __shared__ __align__(16) unsigned short Pq[4][32][72];

  const int bid  = blockIdx.x;
  const int wgid = (bid & 7) * 128 + (bid >> 3);  // bijective XCD swizzle (1024 % 8 == 0)
  const int bh = wgid >> 3;
  const int qt = wgid & 7;
  const int b = bh >> 3, h = bh & 7;
  const int q0 = qt * 128;
  const int t = threadIdx.x, w = t >> 6, l = t & 63;
  const int lr = l & 15, lk = (l >> 4) * 8;
  const size_t base = (size_t)b * 1024 * 768;
  const float scale = 0.17677669529663687f;  // 1/sqrt(32)

  // Q fragments: wave handles 32 q rows (2 x 16)
  bf16x8 qf[2];
#pragma unroll
  for (int qi = 0; qi < 2; qi++)
    qf[qi] = *(const bf16x8*)&qkv[base + (size_t)(q0 + w * 32 + qi * 16 + lr) * 768 + h * 32 + lk];

  f32x4 o[2][2] = {};
  float m[2]    = {0.f, 0.f};     // deferred running max (natural-log domain)
  float lsum[2] = {0.f, 0.f};     // per-lane partial denominators
  const f32x4 z4 = {0.f, 0.f, 0.f, 0.f};

  for (int kc = 0; kc < 16; kc++) {
    const int tok = kc * 64 + (t >> 2);
    const int d0  = (t & 3) * 8;
    const bf16x8 kv_k = *(const bf16x8*)&qkv[base + (size_t)tok * 768 + 256 + h * 32 + d0];
    const bf16x8 kv_v = *(const bf16x8*)&qkv[base + (size_t)tok * 768 + 512 + h * 32 + d0];
    __syncthreads();
    *(bf16x8*)&Ks[t >> 2][d0] = kv_k;
#pragma unroll
    for (int j = 0; j < 8; j++) Vt[d0 + j][t >> 2] = ((const unsigned short*)&kv_v)[j];
    __syncthreads();

    // St = K @ Q^T : lane holds score(q = l&15, key = blk*16 + (l>>4)*4 + r)
    f32x4 s[2][4];
#pragma unroll
    for (int blk = 0; blk < 4; blk++) {
      const bf16x8 kf = *(const bf16x8*)&Ks[blk * 16 + lr][lk];
      s[0][blk] = __builtin_amdgcn_mfma_f32_16x16x32_bf16(kf, qf[0], z4, 0, 0, 0);
      s[1][blk] = __builtin_amdgcn_mfma_f32_16x16x32_bf16(kf, qf[1], z4, 0, 0, 0);
    }

    // defer-max check (T13): local max only + one ballot; slow path rarely taken
    float pm = -3e38f;
#pragma unroll
    for (int qi = 0; qi < 2; qi++)
#pragma unroll
      for (int blk = 0; blk < 4; blk++)
#pragma unroll
        for (int r = 0; r < 4; r++) pm = fmaxf(pm, s[qi][blk][r]);
    if (!__all(pm * scale <= fminf(m[0], m[1]) + 8.f)) {
#pragma unroll
      for (int qi = 0; qi < 2; qi++) {
        float mx = -3e38f;
#pragma unroll
        for (int blk = 0; blk < 4; blk++)
#pragma unroll
          for (int r = 0; r < 4; r++) mx = fmaxf(mx, s[qi][blk][r]);
        mx *= scale;
        mx = fmaxf(mx, __shfl_xor(mx, 16));
        mx = fmaxf(mx, __shfl_xor(mx, 32));
        const float mnew  = fmaxf(m[qi], mx);
        const float delta = m[qi] - mnew;
        lsum[qi] *= __expf(delta);
#pragma unroll
        for (int r = 0; r < 4; r++) {
          const float a = __expf(__shfl(delta, (l >> 4) * 4 + r));
          o[qi][0][r] *= a; o[qi][1][r] *= a;
        }
        m[qi] = mnew;
      }
    }

    // P = exp(S*scale - m); packed b64 LDS writes (keys contiguous along r)
#pragma unroll
    for (int qi = 0; qi < 2; qi++) {
      float ls = 0.f;
#pragma unroll
      for (int blk = 0; blk < 4; blk++) {
        const float p0 = __expf(fmaf(s[qi][blk][0], scale, -m[qi]));
        const float p1 = __expf(fmaf(s[qi][blk][1], scale, -m[qi]));
        const float p2 = __expf(fmaf(s[qi][blk][2], scale, -m[qi]));
        const float p3 = __expf(fmaf(s[qi][blk][3], scale, -m[qi]));
        ls += (p0 + p1) + (p2 + p3);
        ushort4 us;
        us.x = f2bf(p0); us.y = f2bf(p1); us.z = f2bf(p2); us.w = f2bf(p3);
        *(ushort4*)&Pq[w][qi * 16 + lr][blk * 16 + (l >> 4) * 4] = us;
      }
      lsum[qi] += ls;
    }

    // O += P @ V : A = P[q][keys], B = Vt[d][keys]
#pragma unroll
    for (int ks = 0; ks < 2; ks++) {
      const bf16x8 v0f = *(const bf16x8*)&Vt[lr][ks * 32 + lk];
      const bf16x8 v1f = *(const bf16x8*)&Vt[16 + lr][ks * 32 + lk];
#pragma unroll
      for (int qi = 0; qi < 2; qi++) {
        const bf16x8 pa = *(const bf16x8*)&Pq[w][qi * 16 + lr][ks * 32 + lk];
        o[qi][0] = __builtin_amdgcn_mfma_f32_16x16x32_bf16(pa, v0f, o[qi][0], 0, 0, 0);
        o[qi][1] = __builtin_amdgcn_mfma_f32_16x16x32_bf16(pa, v1f, o[qi][1], 0, 0, 0);
      }
    }
  }

  // final: reduce lsum across the 4 lanes sharing each q, then normalize + store
#pragma unroll
  for (int qi = 0; qi < 2; qi++) {
    float lsq = lsum[qi];
    lsq += __shfl_xor(lsq, 16);
    lsq += __shfl_xor(lsq, 32);
#pragma unroll
    for (int r = 0; r < 4; r++) {
      const int qloc = (l >> 4) * 4 + r;
      const float inv = 1.f / __shfl(lsq, qloc);
      const int row = q0 + w * 32 + qi * 16 + qloc;
      attn_out[(size_t)(b * 1024 + row) * 256 + h * 32 + lr]      = f2bf(o[qi][0][r] * inv);
      attn_out[(size_t)(b * 1024 + row) * 256 + h * 32 + 16 + lr] = f2bf(o[qi][1][r] * inv);
    }
  }
}

// ---------------- LN2: y fp32 [tok][256] -> yln bf16 ----------------
__global__ __launch_bounds__(256) void k_ln2(const float* __restrict__ y,
                                             const float* __restrict__ g,
                                             const float* __restrict__ be,
                                             unsigned short* __restrict__ yln) {
  const int row = blockIdx.x * 4 + (threadIdx.x >> 6);
  const int l = threadIdx.x & 63;
  const float* yr = y + (size_t)row * 256;
  const float4 v = *(const float4*)(yr + l * 4);
  float s  = v.x + v.y + v.z + v.w;
  float ss = v.x * v.x + v.y * v.y + v.z * v.z + v.w * v.w;
#pragma unroll
  for (int msk = 1; msk < 64; msk <<= 1) {
    s  += __shfl_xor(s, msk);
    ss += __shfl_xor(ss, msk);
  }
  const float mean = s * (1.f / 256.f);
  const float var  = ss * (1.f / 256.f) - mean * mean;
  const float rs   = rsqrtf(var + 1e-5f);
  const float4 gv  = *(const float4*)(g + l * 4);
  const float4 bv  = *(const float4*)(be + l * 4);
  ushort4 o;
  o.x = f2bf((v.x - mean) * rs * gv.x + bv.x);
  o.y = f2bf((v.y - mean) * rs * gv.y + bv.y);
  o.z = f2bf((v.z - mean) * rs * gv.z + bv.z);
  o.w = f2bf((v.w - mean) * rs * gv.w + bv.w);
  *(ushort4*)&yln[(size_t)row * 256 + l * 4] = o;
}

// ---------------- output transpose: z[b][s][c] -> out[b][c][s] ----------------
__global__ __launch_bounds__(256) void k_tout(const float* __restrict__ z,
                                              float* __restrict__ out) {
  __shared__ float tile[32][33];
  const int b  = blockIdx.z;
  const int c0 = blockIdx.y * 32, p0 = blockIdx.x * 32;
  const int tx = threadIdx.x & 31, ty = threadIdx.x >> 5;
#pragma unroll
  for (int i = 0; i < 32; i += 8)
    tile[ty + i][tx] = z[((size_t)b * 1024 + p0 + ty + i) * 256 + c0 + tx];
  __syncthreads();
#pragma unroll
  for (int i = 0; i < 32; i += 8)
    out[((size_t)b * 256 + c0 + ty + i) * 1024 + p0 + tx] = tile[tx][ty + i];
}

// ---------------- launch ----------------
extern "C" void kernel_launch(void* const* d_in, const int* in_sizes, int n_in,
                              void* d_out, int out_size, void* d_ws, size_t ws_size,
                              hipStream_t stream) {
  const float* x      = (const float*)d_in[0];
  const float* w_qkv  = (const float*)d_in[1];
  const float* w_proj = (const float*)d_in[2];
  const float* b_proj = (const float*)d_in[3];
  const float* g1     = (const float*)d_in[4];
  const float* beta1  = (const float*)d_in[5];
  const float* g2     = (const float*)d_in[6];
  const float* beta2  = (const float*)d_in[7];
  const float* w1     = (const float*)d_in[8];
  const float* b1     = (const float*)d_in[9];
  const float* w2     = (const float*)d_in[10];
  const float* b2     = (const float*)d_in[11];
  float* out = (float*)d_out;
  char* ws = (char*)d_ws;

  constexpr size_t OFF_XT  = 0;                       // 16 MB fp32 [tok][256]
  constexpr size_t OFF_XLN = 16777216;                //  8 MB bf16
  constexpr size_t OFF_QKV = OFF_XLN + 8388608;       // 24 MB bf16 [tok][768]
  constexpr size_t OFF_ATT = OFF_QKV + 25165824;      //  8 MB bf16
  constexpr size_t OFF_Y   = OFF_ATT + 8388608;       // 16 MB fp32
  constexpr size_t OFF_YLN = OFF_Y + 16777216;        //  8 MB bf16
  constexpr size_t OFF_W   = OFF_YLN + 8388608;       // weights bf16
  constexpr size_t OFF_H1  = OFF_XLN;                 // alias: 32 MB bf16 [tok][1024]
  constexpr size_t OFF_Z   = OFF_XT;                  // alias: 16 MB fp32

  float*          xt    = (float*)(ws + OFF_XT);
  unsigned short* xln   = (unsigned short*)(ws + OFF_XLN);
  unsigned short* qkv   = (unsigned short*)(ws + OFF_QKV);
  unsigned short* attn  = (unsigned short*)(ws + OFF_ATT);
  float*          y     = (float*)(ws + OFF_Y);
  unsigned short* yln   = (unsigned short*)(ws + OFF_YLN);
  unsigned short* h1    = (unsigned short*)(ws + OFF_H1);
  float*          z     = (float*)(ws + OFF_Z);
  unsigned short* wqkvb = (unsigned short*)(ws + OFF_W);
  unsigned short* wprjb = (unsigned short*)(ws + OFF_W + 393216);
  unsigned short* w1b   = (unsigned short*)(ws + OFF_W + 393216 + 131072);
  unsigned short* w2b   = (unsigned short*)(ws + OFF_W + 393216 + 131072 + 524288);

  k_f2bf<<<768, 256, 0, stream>>>(w_qkv, wqkvb, 768 * 256);
  k_f2bf<<<256, 256, 0, stream>>>(w_proj, wprjb, 256 * 256);
  k_f2bf<<<1024, 256, 0, stream>>>(w1, w1b, 1024 * 256);
  k_f2bf<<<1024, 256, 0, stream>>>(w2, w2b, 256 * 1024);

  k_ln1<<<dim3(32, 16), 256, 0, stream>>>(x, g1, beta1, xt, xln);

  k_gemm<0><<<dim3(128, 6), 256, 0, stream>>>(xln, 256, wqkvb, 256, 256,
                                              nullptr, nullptr, 0, nullptr, qkv, 768);

  k_attn<<<1024, 256, 0, stream>>>(qkv, attn);

  k_gemm<1><<<dim3(128, 2), 256, 0, stream>>>(attn, 256, wprjb, 256, 256,
                                              b_proj, xt, 256, y, nullptr, 256);

  k_ln2<<<4096, 256, 0, stream>>>(y, g2, beta2, yln);

  k_gemm<2><<<dim3(128, 8), 256, 0, stream>>>(yln, 256, w1b, 256, 256,
                                              b1, nullptr, 0, nullptr, h1, 1024);

  k_gemm<3><<<dim3(128, 2), 256, 0, stream>>>(h1, 1024, w2b, 1024, 1024,
                                              b2, y, 256, z, nullptr, 256);

  k_tout<<<dim3(32, 8, 16), 256, 0, stream>>>(z, out);
}